// Round 13
// baseline (24.479 us; speedup 1.0000x reference)
//
#include <hip/hip_runtime.h>

#define GAMMA 0.99f
#define TAU   0.95f
#define GTAU  (GAMMA * TAU)

constexpr int WSEQ   = 8;            // elements per lane (two float4)
constexpr int WCHUNK = 64 * WSEQ;    // 512 elements per wave
constexpr int BLK    = 256;          // 4 independent waves per block

typedef float fx4 __attribute__((ext_vector_type(4)));   // clang vector: OK for nontemporal builtin

// (A,B) = (A,B) ∘ (rA,rB)  — apply right operand first, then (A,B)
__device__ __forceinline__ void post_compose(float& A, float& B, float rA, float rB) {
    B = fmaf(A, rB, B);
    A *= rA;
}
// (A,B) = (lA,lB) ∘ (A,B)  — apply (A,B) first, then left operand
__device__ __forceinline__ void pre_compose(float& A, float& B, float lA, float lB) {
    B = fmaf(lA, B, lB);
    A *= lA;
}

// =====================================================================
// Fully wave-independent GAE scan: each wave owns a 512-element chunk.
// No __syncthreads, no LDS, no cross-wave/block communication.
//  - lane i owns 8 contiguous elements via two float4 loads (stride
//    32B/lane; the instruction pair fully covers each 64B line ->
//    line-level coalescing preserved).
//  - carry: at m[i]==0 both recurrences reset (map A=0 annihilates all
//    later terms), so composing element maps rightward from p (next
//    chunk start) to the first m==0 or array end gives the EXACT carry.
//    Bernoulli masks -> first 64-wide batch suffices with prob 1-2^-64
//    (loop continues otherwise; correct for any data).
//  - outputs stored non-temporally (never re-read; keep LLC for inputs
//    which ARE re-read as neighbor carry windows).
// =====================================================================
__global__ __launch_bounds__(BLK) void k_wave(
    const float* __restrict__ r, const float* __restrict__ v,
    const float* __restrict__ nv, const int* __restrict__ m,
    float* __restrict__ out_adv, float* __restrict__ out_ret, int T, int nchunk)
{
    const int  lane  = threadIdx.x & 63;
    const int  w     = threadIdx.x >> 6;
    const int  chunk = (int)blockIdx.x * 4 + w;
    if (chunk >= nchunk) return;                      // wave-uniform exit

    const long base = (long)chunk * WCHUNK + (long)lane * WSEQ;
    const long p    = (long)(chunk + 1) * WCHUNK;     // next chunk start

    // ---- carry-window prefetch: issue early, all 64 lanes ----
    float pm = 0.f, pr = 0.f, pv = 0.f, pv1 = 0.f, pnv = 0.f;
    if (p < (long)T) {
        long i = p + lane;
        if (i < (long)T) {
            pm  = (float)m[i];
            pr  = r[i];
            pv  = v[i];
            pv1 = (i + 1 < (long)T) ? v[i + 1] : 0.f;
            pnv = nv[i];
        }
    }

    // ---------------- Phase A: load chunk + per-element maps ----------------
    float delta[WSEQ], dd[WSEQ];
    unsigned vbits = 0, mbits = 0;
    float Aa = 1.f, Ba = 0.f, Ar = 1.f, Br = 0.f;
    const bool full = (p <= (long)T);                 // whole chunk in range

    if (full) {
        vbits = 0xFFu;
        float4 r4a = *(const float4*)(r  + base);
        float4 r4b = *(const float4*)(r  + base + 4);
        float4 v4a = *(const float4*)(v  + base);
        float4 v4b = *(const float4*)(v  + base + 4);
        float4 n4a = *(const float4*)(nv + base);
        float4 n4b = *(const float4*)(nv + base + 4);
        int4   m4a = *(const int4*)  (m  + base);
        int4   m4b = *(const int4*)  (m  + base + 4);

        float vhi   = __shfl(pv, 0);                  // v[p] (0 if p>=T)
        float vnext = __shfl_down(v4a.x, 1);          // lane+1's v[base]
        if (lane == 63) vnext = vhi;

        float rr[8]  = {r4a.x, r4a.y, r4a.z, r4a.w, r4b.x, r4b.y, r4b.z, r4b.w};
        float vv[9]  = {v4a.x, v4a.y, v4a.z, v4a.w, v4b.x, v4b.y, v4b.z, v4b.w, vnext};
        float nn[8]  = {n4a.x, n4a.y, n4a.z, n4a.w, n4b.x, n4b.y, n4b.z, n4b.w};
        float fmv[8] = {(float)m4a.x, (float)m4a.y, (float)m4a.z, (float)m4a.w,
                        (float)m4b.x, (float)m4b.y, (float)m4b.z, (float)m4b.w};
        #pragma unroll
        for (int i = WSEQ - 1; i >= 0; --i) {
            if (fmv[i] != 0.f) mbits |= (1u << i);
            delta[i] = rr[i] + GAMMA * fmv[i] * vv[i+1] - vv[i];
            dd[i]    = rr[i] + GAMMA * (1.f - fmv[i]) * nn[i];
            pre_compose(Aa, Ba, GTAU  * fmv[i], delta[i]);
            pre_compose(Ar, Br, GAMMA * fmv[i], dd[i]);
        }
    } else {
        #pragma unroll
        for (int ii = 0; ii < WSEQ; ++ii) {
            int i = WSEQ - 1 - ii;
            long idx = base + i;
            bool val = idx < (long)T;
            float rr  = val ? r[idx]  : 0.f;
            float vv0 = val ? v[idx]  : 0.f;
            float vv1 = (idx + 1 < (long)T) ? v[idx + 1] : 0.f;
            float nn  = val ? nv[idx] : 0.f;
            float fmv = val ? (float)m[idx] : 0.f;
            if (val) vbits |= (1u << i);
            if (val && fmv != 0.f) mbits |= (1u << i);
            delta[i] = val ? (rr + GAMMA * fmv * vv1 - vv0) : 0.f;
            dd[i]    = val ? (rr + GAMMA * (1.f - fmv) * nn) : 0.f;
            pre_compose(Aa, Ba, val ? GTAU * fmv  : 1.f, delta[i]);
            pre_compose(Ar, Br, val ? GAMMA * fmv : 1.f, dd[i]);
        }
    }

    // wave-level inclusive suffix scan (contiguous segments, non-commutative OK)
    #pragma unroll
    for (int st = 1; st < 64; st <<= 1) {
        float oAa = __shfl_down(Aa, st);
        float oBa = __shfl_down(Ba, st);
        float oAr = __shfl_down(Ar, st);
        float oBr = __shfl_down(Br, st);
        if (lane + st < 64) {
            post_compose(Aa, Ba, oAa, oBa);
            post_compose(Ar, Br, oAr, oBr);
        }
    }
    // thread-exclusive (within wave)
    float eAa = __shfl_down(Aa, 1);
    float eBa = __shfl_down(Ba, 1);
    float eAr = __shfl_down(Ar, 1);
    float eBr = __shfl_down(Br, 1);
    if (lane == 63) { eAa=1.f; eBa=0.f; eAr=1.f; eBr=0.f; }

    // ---- Carry: compose element maps from p to first m==0 (all lanes) ----
    float cbA = 0.f, cbR = 0.f;
    if (p < (long)T) {
        float MAa, MBa, MAr, MBr;
        // first batch: prefetched
        {
            long i = p + lane;
            bool have = i < (long)T;
            float aA=1.f, aB=0.f, rA_=1.f, rB_=0.f;
            if (have) {
                aA  = GTAU * pm;
                aB  = pr + GAMMA * pm * pv1 - pv;
                rA_ = GAMMA * pm;
                rB_ = pr + GAMMA * (1.f - pm) * pnv;
            }
            bool term = (!have) || (pm == 0.f);
            unsigned long long bz = __ballot(term);
            #pragma unroll
            for (int st = 1; st < 64; st <<= 1) {
                float oAa = __shfl_down(aA,  st);
                float oBa = __shfl_down(aB,  st);
                float oAr = __shfl_down(rA_, st);
                float oBr = __shfl_down(rB_, st);
                if (lane + st < 64) {
                    post_compose(aA,  aB,  oAa, oBa);
                    post_compose(rA_, rB_, oAr, oBr);
                }
            }
            MAa = __shfl(aA, 0);  MBa = __shfl(aB, 0);
            MAr = __shfl(rA_, 0); MBr = __shfl(rB_, 0);
            if (bz == 0ull) {
                // rare: continue past the first 64 elements
                for (long jb = p + 64; ; jb += 64) {
                    long i2 = jb + lane;
                    bool have2 = i2 < (long)T;
                    float aA2=1.f, aB2=0.f, rA2=1.f, rB2=0.f;
                    float mi = 0.f;
                    if (have2) {
                        mi = (float)m[i2];
                        float ri  = r[i2];
                        float vi  = v[i2];
                        float vi1 = (i2 + 1 < (long)T) ? v[i2 + 1] : 0.f;
                        float nvi = nv[i2];
                        aA2 = GTAU * mi;
                        aB2 = ri + GAMMA * mi * vi1 - vi;
                        rA2 = GAMMA * mi;
                        rB2 = ri + GAMMA * (1.f - mi) * nvi;
                    }
                    bool term2 = (!have2) || (mi == 0.f);
                    unsigned long long bz2 = __ballot(term2);
                    #pragma unroll
                    for (int st = 1; st < 64; st <<= 1) {
                        float oAa = __shfl_down(aA2, st);
                        float oBa = __shfl_down(aB2, st);
                        float oAr = __shfl_down(rA2, st);
                        float oBr = __shfl_down(rB2, st);
                        if (lane + st < 64) {
                            post_compose(aA2, aB2, oAa, oBa);
                            post_compose(rA2, rB2, oAr, oBr);
                        }
                    }
                    float bAa = __shfl(aA2, 0), bBa = __shfl(aB2, 0);
                    float bAr = __shfl(rA2, 0), bBr = __shfl(rB2, 0);
                    post_compose(MAa, MBa, bAa, bBa);
                    post_compose(MAr, MBr, bAr, bBr);
                    if (bz2 != 0ull) break;
                }
            }
        }
        cbA = MBa;   // adv[p]  (M applied to 0)
        cbR = MBr;   // ret[p]
    }

    // ---------------- Phase C: replay + store (coalesced, non-temporal) ----------------
    float xa = fmaf(eAa, cbA, eBa);   // value at this thread's right edge
    float xr = fmaf(eAr, cbR, eBr);

    if (full) {
        float ta[8], tr[8];
        #pragma unroll
        for (int i = WSEQ - 1; i >= 0; --i) {
            float a  = (mbits >> i & 1u) ? GTAU  : 0.f;
            float cc = (mbits >> i & 1u) ? GAMMA : 0.f;
            xa = fmaf(a,  xa, delta[i]);
            xr = fmaf(cc, xr, dd[i]);
            ta[i] = xa; tr[i] = xr;
        }
        fx4 va0 = {ta[0], ta[1], ta[2], ta[3]};
        fx4 va1 = {ta[4], ta[5], ta[6], ta[7]};
        fx4 vr0 = {tr[0], tr[1], tr[2], tr[3]};
        fx4 vr1 = {tr[4], tr[5], tr[6], tr[7]};
        __builtin_nontemporal_store(va0, (fx4*)(out_adv + base));
        __builtin_nontemporal_store(va1, (fx4*)(out_adv + base + 4));
        __builtin_nontemporal_store(vr0, (fx4*)(out_ret + base));
        __builtin_nontemporal_store(vr1, (fx4*)(out_ret + base + 4));
    } else {
        #pragma unroll
        for (int i = WSEQ - 1; i >= 0; --i) {
            bool val = (vbits >> i) & 1u;
            float a  = val ? ((mbits >> i & 1u) ? GTAU  : 0.f) : 1.f;
            float cc = val ? ((mbits >> i & 1u) ? GAMMA : 0.f) : 1.f;
            xa = fmaf(a,  xa, delta[i]);
            xr = fmaf(cc, xr, dd[i]);
            if (base + i < (long)T) {
                out_adv[base + i] = xa;
                out_ret[base + i] = xr;
            }
        }
    }
}

extern "C" void kernel_launch(void* const* d_in, const int* in_sizes, int n_in,
                              void* d_out, int out_size, void* d_ws, size_t ws_size,
                              hipStream_t stream) {
    const float* r  = (const float*)d_in[0];
    const float* v  = (const float*)d_in[1];
    const float* nv = (const float*)d_in[2];
    const int*   m  = (const int*)d_in[3];
    const int T = in_sizes[0];
    const int nchunk = (T + WCHUNK - 1) / WCHUNK;   // 8192 for T = 2^22
    const int nblk   = (nchunk + 3) / 4;

    float* out_adv = (float*)d_out;
    float* out_ret = (float*)d_out + T;

    k_wave<<<nblk, BLK, 0, stream>>>(r, v, nv, m, out_adv, out_ret, T, nchunk);
}

// Round 14
// 22.401 us; speedup vs baseline: 1.0928x; 1.0928x over previous
//
#include <hip/hip_runtime.h>

#define GAMMA 0.99f
#define TAU   0.95f
#define GTAU  (GAMMA * TAU)

constexpr int WSEQ   = 4;            // elements per lane (one float4)
constexpr int WCHUNK = 64 * WSEQ;    // 256 elements per wave
constexpr int BLK    = 256;          // 4 independent waves per block

typedef float fx4 __attribute__((ext_vector_type(4)));   // clang vector: OK for nontemporal builtin

// (A,B) = (A,B) ∘ (rA,rB)  — apply right operand first, then (A,B)
__device__ __forceinline__ void post_compose(float& A, float& B, float rA, float rB) {
    B = fmaf(A, rB, B);
    A *= rA;
}
// (A,B) = (lA,lB) ∘ (A,B)  — apply (A,B) first, then left operand
__device__ __forceinline__ void pre_compose(float& A, float& B, float lA, float lB) {
    B = fmaf(lA, B, lB);
    A *= lA;
}

// =====================================================================
// Round-11 structure (verified 22.8us) with ONE change: non-temporal
// output stores. Each wave owns a 256-element chunk; no __syncthreads,
// no LDS, no cross-wave/block communication.
//  - lane i's float4 at base + i*16B: perfectly coalesced.
//  - carry: at m[i]==0 both recurrences reset (map A=0 annihilates all
//    later terms), so composing element maps rightward from p (next
//    chunk start) to the first m==0 or array end gives the EXACT carry.
//    Bernoulli masks -> first 64-wide batch suffices with prob 1-2^-64.
//  - outputs stored non-temporally (never re-read; keeps LLC for the
//    inputs which ARE re-read as neighbor carry windows).
// =====================================================================
__global__ __launch_bounds__(BLK) void k_wave(
    const float* __restrict__ r, const float* __restrict__ v,
    const float* __restrict__ nv, const int* __restrict__ m,
    float* __restrict__ out_adv, float* __restrict__ out_ret, int T, int nchunk)
{
    const int  lane  = threadIdx.x & 63;
    const int  w     = threadIdx.x >> 6;
    const int  chunk = (int)blockIdx.x * 4 + w;
    if (chunk >= nchunk) return;                      // wave-uniform exit

    const long base = (long)chunk * WCHUNK + (long)lane * WSEQ;
    const long p    = (long)(chunk + 1) * WCHUNK;     // next chunk start

    // ---- carry-window prefetch: issue early, all 64 lanes ----
    float pm = 0.f, pr = 0.f, pv = 0.f, pv1 = 0.f, pnv = 0.f;
    if (p < (long)T) {
        long i = p + lane;
        if (i < (long)T) {
            pm  = (float)m[i];
            pr  = r[i];
            pv  = v[i];
            pv1 = (i + 1 < (long)T) ? v[i + 1] : 0.f;
            pnv = nv[i];
        }
    }

    // ---------------- Phase A: load chunk + per-element maps ----------------
    float delta[WSEQ], dd[WSEQ];
    unsigned vbits = 0, mbits = 0;
    float Aa = 1.f, Ba = 0.f, Ar = 1.f, Br = 0.f;
    const bool full = (p <= (long)T);                 // whole chunk in range

    if (full) {
        vbits = 0xFu;
        float4 r4 = *(const float4*)(r  + base);
        float4 v4 = *(const float4*)(v  + base);
        float4 n4 = *(const float4*)(nv + base);
        int4   m4 = *(const int4*)  (m  + base);
        float vhi   = __shfl(pv, 0);                  // v[p] (0 if p>=T)
        float vnext = __shfl_down(v4.x, 1);           // lane+1's v[base]
        if (lane == 63) vnext = vhi;

        float rr[4]  = {r4.x, r4.y, r4.z, r4.w};
        float vv[5]  = {v4.x, v4.y, v4.z, v4.w, vnext};
        float nn[4]  = {n4.x, n4.y, n4.z, n4.w};
        float fmv[4] = {(float)m4.x, (float)m4.y, (float)m4.z, (float)m4.w};
        #pragma unroll
        for (int i = WSEQ - 1; i >= 0; --i) {
            if (fmv[i] != 0.f) mbits |= (1u << i);
            delta[i] = rr[i] + GAMMA * fmv[i] * vv[i+1] - vv[i];
            dd[i]    = rr[i] + GAMMA * (1.f - fmv[i]) * nn[i];
            pre_compose(Aa, Ba, GTAU  * fmv[i], delta[i]);
            pre_compose(Ar, Br, GAMMA * fmv[i], dd[i]);
        }
    } else {
        #pragma unroll
        for (int ii = 0; ii < WSEQ; ++ii) {
            int i = WSEQ - 1 - ii;
            long idx = base + i;
            bool val = idx < (long)T;
            float rr  = val ? r[idx]  : 0.f;
            float vv0 = val ? v[idx]  : 0.f;
            float vv1 = (idx + 1 < (long)T) ? v[idx + 1] : 0.f;
            float nn  = val ? nv[idx] : 0.f;
            float fmv = val ? (float)m[idx] : 0.f;
            if (val) vbits |= (1u << i);
            if (val && fmv != 0.f) mbits |= (1u << i);
            delta[i] = val ? (rr + GAMMA * fmv * vv1 - vv0) : 0.f;
            dd[i]    = val ? (rr + GAMMA * (1.f - fmv) * nn) : 0.f;
            pre_compose(Aa, Ba, val ? GTAU * fmv  : 1.f, delta[i]);
            pre_compose(Ar, Br, val ? GAMMA * fmv : 1.f, dd[i]);
        }
    }

    // wave-level inclusive suffix scan (contiguous segments, non-commutative OK)
    #pragma unroll
    for (int st = 1; st < 64; st <<= 1) {
        float oAa = __shfl_down(Aa, st);
        float oBa = __shfl_down(Ba, st);
        float oAr = __shfl_down(Ar, st);
        float oBr = __shfl_down(Br, st);
        if (lane + st < 64) {
            post_compose(Aa, Ba, oAa, oBa);
            post_compose(Ar, Br, oAr, oBr);
        }
    }
    // thread-exclusive (within wave)
    float eAa = __shfl_down(Aa, 1);
    float eBa = __shfl_down(Ba, 1);
    float eAr = __shfl_down(Ar, 1);
    float eBr = __shfl_down(Br, 1);
    if (lane == 63) { eAa=1.f; eBa=0.f; eAr=1.f; eBr=0.f; }

    // ---- Carry: compose element maps from p to first m==0 (all lanes) ----
    float cbA = 0.f, cbR = 0.f;
    if (p < (long)T) {
        float MAa, MBa, MAr, MBr;
        // first batch: prefetched
        {
            long i = p + lane;
            bool have = i < (long)T;
            float aA=1.f, aB=0.f, rA_=1.f, rB_=0.f;
            if (have) {
                aA  = GTAU * pm;
                aB  = pr + GAMMA * pm * pv1 - pv;
                rA_ = GAMMA * pm;
                rB_ = pr + GAMMA * (1.f - pm) * pnv;
            }
            bool term = (!have) || (pm == 0.f);
            unsigned long long bz = __ballot(term);
            #pragma unroll
            for (int st = 1; st < 64; st <<= 1) {
                float oAa = __shfl_down(aA,  st);
                float oBa = __shfl_down(aB,  st);
                float oAr = __shfl_down(rA_, st);
                float oBr = __shfl_down(rB_, st);
                if (lane + st < 64) {
                    post_compose(aA,  aB,  oAa, oBa);
                    post_compose(rA_, rB_, oAr, oBr);
                }
            }
            MAa = __shfl(aA, 0);  MBa = __shfl(aB, 0);
            MAr = __shfl(rA_, 0); MBr = __shfl(rB_, 0);
            if (bz == 0ull) {
                // rare: continue past the first 64 elements
                for (long jb = p + 64; ; jb += 64) {
                    long i2 = jb + lane;
                    bool have2 = i2 < (long)T;
                    float aA2=1.f, aB2=0.f, rA2=1.f, rB2=0.f;
                    float mi = 0.f;
                    if (have2) {
                        mi = (float)m[i2];
                        float ri  = r[i2];
                        float vi  = v[i2];
                        float vi1 = (i2 + 1 < (long)T) ? v[i2 + 1] : 0.f;
                        float nvi = nv[i2];
                        aA2 = GTAU * mi;
                        aB2 = ri + GAMMA * mi * vi1 - vi;
                        rA2 = GAMMA * mi;
                        rB2 = ri + GAMMA * (1.f - mi) * nvi;
                    }
                    bool term2 = (!have2) || (mi == 0.f);
                    unsigned long long bz2 = __ballot(term2);
                    #pragma unroll
                    for (int st = 1; st < 64; st <<= 1) {
                        float oAa = __shfl_down(aA2, st);
                        float oBa = __shfl_down(aB2, st);
                        float oAr = __shfl_down(rA2, st);
                        float oBr = __shfl_down(rB2, st);
                        if (lane + st < 64) {
                            post_compose(aA2, aB2, oAa, oBa);
                            post_compose(rA2, rB2, oAr, oBr);
                        }
                    }
                    float bAa = __shfl(aA2, 0), bBa = __shfl(aB2, 0);
                    float bAr = __shfl(rA2, 0), bBr = __shfl(rB2, 0);
                    post_compose(MAa, MBa, bAa, bBa);
                    post_compose(MAr, MBr, bAr, bBr);
                    if (bz2 != 0ull) break;
                }
            }
        }
        cbA = MBa;   // adv[p]  (M applied to 0)
        cbR = MBr;   // ret[p]
    }

    // ---------------- Phase C: replay + store (coalesced, non-temporal) ----------------
    float xa = fmaf(eAa, cbA, eBa);   // value at this thread's right edge
    float xr = fmaf(eAr, cbR, eBr);

    if (full) {
        float ta[4], tr[4];
        #pragma unroll
        for (int i = WSEQ - 1; i >= 0; --i) {
            float a  = (mbits >> i & 1u) ? GTAU  : 0.f;
            float cc = (mbits >> i & 1u) ? GAMMA : 0.f;
            xa = fmaf(a,  xa, delta[i]);
            xr = fmaf(cc, xr, dd[i]);
            ta[i] = xa; tr[i] = xr;
        }
        fx4 va = {ta[0], ta[1], ta[2], ta[3]};
        fx4 vr = {tr[0], tr[1], tr[2], tr[3]};
        __builtin_nontemporal_store(va, (fx4*)(out_adv + base));
        __builtin_nontemporal_store(vr, (fx4*)(out_ret + base));
    } else {
        #pragma unroll
        for (int i = WSEQ - 1; i >= 0; --i) {
            bool val = (vbits >> i) & 1u;
            float a  = val ? ((mbits >> i & 1u) ? GTAU  : 0.f) : 1.f;
            float cc = val ? ((mbits >> i & 1u) ? GAMMA : 0.f) : 1.f;
            xa = fmaf(a,  xa, delta[i]);
            xr = fmaf(cc, xr, dd[i]);
            if (base + i < (long)T) {
                out_adv[base + i] = xa;
                out_ret[base + i] = xr;
            }
        }
    }
}

extern "C" void kernel_launch(void* const* d_in, const int* in_sizes, int n_in,
                              void* d_out, int out_size, void* d_ws, size_t ws_size,
                              hipStream_t stream) {
    const float* r  = (const float*)d_in[0];
    const float* v  = (const float*)d_in[1];
    const float* nv = (const float*)d_in[2];
    const int*   m  = (const int*)d_in[3];
    const int T = in_sizes[0];
    const int nchunk = (T + WCHUNK - 1) / WCHUNK;   // 16384 for T = 2^22
    const int nblk   = (nchunk + 3) / 4;

    float* out_adv = (float*)d_out;
    float* out_ret = (float*)d_out + T;

    k_wave<<<nblk, BLK, 0, stream>>>(r, v, nv, m, out_adv, out_ret, T, nchunk);
}